// Round 3
// baseline (92.730 us; speedup 1.0000x reference)
//
#include <hip/hip_runtime.h>
#include <hip/hip_bf16.h>

// Problem constants (from reference setup_inputs)
#define LATDIM 128     // d
#define ANUM   64      // anchor sets A
#define NNODES 10000   // N
#define PERIOD 625     // N / gcd(A, N) = 10000/16 : period of (64*i mod 10000)
#define TN     32      // n-tile per block in main kernel

// ---------------------------------------------------------------------------
// Dtypes (evidence r0-r2): ALL float tensors are fp32 (bf16 reads → NaN in
// r1: fp32 bit-halves alias bf16 NaN encodings). Output is fp32 too — r2
// wrote packed bf16 into the fp32 buffer and produced error 0.646 ==
// exactly the "uncorrelated same-scale + zero tail" prediction. Contract:
// reference output dtype is float32 -> float*.
//
// Decomposition (re-derived and verified line-by-line in r2 post-mortem):
//   out[n,o] = (1/A) * sum_a dists[a,n] * P[a,o]   +  T2b[n % 625, o]
//   P[a,o]   = sum_k E[anchor[a],k] * W[o,k]                (k <  d half)
//   T2b[s,o] = b[o] + (1/A) * sum_k S[s,k] * W[o, d+k]      (k >= d half)
//   S[s,k]   = sum_{a<64} E[(64*s + a) % N, k]   (self_feature row-sums,
//              period 625 because gcd(64,10000)=16)
// Work: ~180 MFLOP, ~13 MB HBM traffic — launch-overhead territory.
// ---------------------------------------------------------------------------

// Blocks [0,64): compute P[a][o].  Blocks [64, 64+625): compute T2b[s][o].
__global__ __launch_bounds__(128) void prep_kernel(
    const float* __restrict__ embeds,   // [N, d] fp32
    const float* __restrict__ W,        // [d, 2d] row-major fp32
    const float* __restrict__ b,        // [d] fp32
    const int*   __restrict__ anchor,   // [A] int32
    float* __restrict__ P,              // [A, d]   (ws)
    float* __restrict__ T2b)            // [625, d] (ws)
{
    const int tid = threadIdx.x;   // 0..127 == output channel o (or column k)
    if (blockIdx.x < ANUM) {
        const int a = blockIdx.x;
        __shared__ float e_s[LATDIM];
        const int row = anchor[a];
        e_s[tid] = embeds[row * LATDIM + tid];
        __syncthreads();
        const float* w = W + tid * (2 * LATDIM);   // W[o, 0..d)
        float acc = 0.f;
        #pragma unroll
        for (int k = 0; k < LATDIM; ++k)
            acc += e_s[k] * w[k];
        P[a * LATDIM + tid] = acc;
    } else {
        const int s = blockIdx.x - ANUM;
        __shared__ float S_s[LATDIM];
        float acc = 0.f;
        const int base = s * ANUM;                 // < 40000
        #pragma unroll 4
        for (int a2 = 0; a2 < ANUM; ++a2) {
            int r = (base + a2) % NNODES;          // wraparound rows
            acc += embeds[r * LATDIM + tid];       // coalesced across tid
        }
        S_s[tid] = acc;
        __syncthreads();
        const float* w2 = W + tid * (2 * LATDIM) + LATDIM;  // W[o, d..2d)
        float dot = 0.f;
        #pragma unroll
        for (int k = 0; k < LATDIM; ++k)
            dot += S_s[k] * w2[k];
        T2b[s * LATDIM + tid] = b[tid] + dot * (1.0f / ANUM);
    }
}

// Main: out[n,o] = (1/A) * sum_a D[a,n] * P[a,o] + T2b[n%625, o]
// Block: 256 threads; o = tid&127, ni = tid>>7 (2 interleaved n-groups).
// P (32 KB) + a 64x32 dists tile (8 KB) staged in LDS; P reused from a
// register across the 16 n's each thread owns; D reads are LDS broadcasts.
__global__ __launch_bounds__(256) void main_kernel(
    const float* __restrict__ dists,    // [A, N] fp32
    const float* __restrict__ P,        // [A, d]
    const float* __restrict__ T2b,      // [625, d]
    float* __restrict__ out)            // [N, d] fp32
{
    __shared__ float P_s[ANUM * LATDIM];   // 32 KB
    __shared__ float D_s[ANUM][TN];        // 8 KB
    const int tid = threadIdx.x;
    const int n0  = blockIdx.x * TN;

    // Stage P (coalesced, 32 floats/thread)
    #pragma unroll
    for (int i = 0; i < (ANUM * LATDIM) / 256; ++i)
        P_s[tid + i * 256] = P[tid + i * 256];

    // Stage dists tile: D_s[a][nl] = dists[a*N + n0 + nl]  (coalesced per 32)
    #pragma unroll
    for (int i = 0; i < (ANUM * TN) / 256; ++i) {
        int idx = tid + i * 256;
        int a  = idx / TN;
        int nl = idx % TN;
        int n  = n0 + nl;
        D_s[a][nl] = (n < NNODES) ? dists[a * NNODES + n] : 0.f;
    }
    __syncthreads();

    const int o  = tid & (LATDIM - 1);
    const int ni = tid >> 7;              // 0 or 1

    float acc[TN / 2];
    #pragma unroll
    for (int j = 0; j < TN / 2; ++j) acc[j] = 0.f;

    for (int a = 0; a < ANUM; ++a) {
        const float p = P_s[a * LATDIM + o];          // coalesced LDS read
        #pragma unroll
        for (int j = 0; j < TN / 2; ++j)
            acc[j] += D_s[a][ni + 2 * j] * p;         // broadcast LDS read
    }

    #pragma unroll
    for (int j = 0; j < TN / 2; ++j) {
        const int n = n0 + ni + 2 * j;
        if (n < NNODES) {
            out[n * LATDIM + o] =
                acc[j] * (1.0f / ANUM) + T2b[(n % PERIOD) * LATDIM + o];
        }
    }
}

extern "C" void kernel_launch(void* const* d_in, const int* in_sizes, int n_in,
                              void* d_out, int out_size, void* d_ws, size_t ws_size,
                              hipStream_t stream) {
    const float* embeds = (const float*)d_in[0];   // [10000,128] fp32
    const float* dists  = (const float*)d_in[1];   // [64,10000]  fp32
    const float* W      = (const float*)d_in[2];   // [128,256]   fp32
    const float* b      = (const float*)d_in[3];   // [128]       fp32
    const int*   anchor = (const int*)d_in[4];     // [64]        int32
    float* out = (float*)d_out;                    // [10000,128] fp32

    float* P   = (float*)d_ws;            // 64*128 floats   = 32 KB
    float* T2b = P + ANUM * LATDIM;       // 625*128 floats  = 320 KB
    // ws needed: 352,768 bytes total

    prep_kernel<<<ANUM + PERIOD, 128, 0, stream>>>(embeds, W, b, anchor, P, T2b);
    main_kernel<<<(NNODES + TN - 1) / TN, 256, 0, stream>>>(dists, P, T2b, out);
}

// Round 4
// 84.214 us; speedup vs baseline: 1.1011x; 1.1011x over previous
//
#include <hip/hip_runtime.h>

// Problem constants (from reference setup_inputs)
#define LATDIM 128     // d
#define ANUM   64      // anchor sets A
#define NNODES 10000   // N
#define PERIOD 625     // N / gcd(A,N): period of (64*i mod 10000)
#define TN     32      // n per main block (2 chunks of 16, one per wave-pair)
#define PPB    8       // anchors per P-block
#define SPB    4       // s-values per T2-block
#define PBLK   (ANUM / PPB)                 // 8 blocks
#define TBLK   ((PERIOD + SPB - 1) / SPB)   // 157 blocks
#define WPAD   33      // W_s row stride in float4 units (132 floats)

// ---------------------------------------------------------------------------
// Verified decomposition (r3 passed, absmax 9.8e-4):
//   out[n,o] = (1/A) * sum_a dists[a,n] * P[a,o]  +  T2b[n % 625, o]
//   P[a,o]   = sum_k E[anchor[a],k] * W[o,k]
//   T2b[s,o] = b[o] + (1/A) * sum_k S[s,k] * W[o,128+k],
//   S[s,k]   = sum_a E[(64s+a) % N, k]
//
// r3 perf analysis: prep was L1-lookup-bound (uncoalesced W row reads: 64
// lines per wave-inst, ~18 us); main was LDS-issue-bound (17 scalar ds
// broadcasts per a-iter, ~10 us vs 1 us FMA floor). This version:
//  - prep: W-half staged in LDS as W_s[o][k] with 132-float row pad ->
//    conflict-free ds_{read,write}_b128; fat blocks amortize staging.
//  - main: no D_s at all; d-values are wave-uniform -> scalar-path loads
//    (readfirstlane-uniform base), LDS only holds P (b32 conflict-free).
// ---------------------------------------------------------------------------

__global__ __launch_bounds__(128) void prep_kernel(
    const float* __restrict__ embeds,   // [N, d] fp32
    const float* __restrict__ W,        // [d, 2d] fp32 row-major
    const float* __restrict__ b,        // [d] fp32
    const int*   __restrict__ anchor,   // [A] int32
    float* __restrict__ P,              // [A, d]   (ws)
    float* __restrict__ T2b)            // [625, d] (ws)
{
    __shared__ float W_s[128 * 4 * WPAD];    // 128 rows x 132 floats = 66 KB
    __shared__ float X_s[PPB][LATDIM];       // anchor rows (P) or S sums (T2)
    const int tid = threadIdx.x;             // 0..127
    const bool isP = (blockIdx.x < PBLK);
    const int off = isP ? 0 : LATDIM;        // which W half

    // Stage W-half into LDS: W_s[r*132 + k] = W[r*256 + off + k].
    // Global: float4, fully coalesced. LDS: ds_write_b128, start bank
    // 4*(r+c4) -> each 8-lane group covers all 32 banks: conflict-free.
    {
        float4* W_s4 = (float4*)W_s;
        #pragma unroll
        for (int it = 0; it < 32; ++it) {
            int f  = it * 128 + tid;     // 0..4095 (4096 float4s)
            int r  = f >> 5;             // row 0..127
            int c4 = f & 31;             // float4 col 0..31
            float4 v = *(const float4*)(W + r * (2 * LATDIM) + off + 4 * c4);
            W_s4[r * WPAD + c4] = v;
        }
    }

    if (isP) {
        const int a0 = blockIdx.x * PPB;
        #pragma unroll
        for (int j = 0; j < PPB; ++j)
            X_s[j][tid] = embeds[(size_t)anchor[a0 + j] * LATDIM + tid];
        __syncthreads();   // covers W_s too

        float acc[PPB] = {};
        const float4* W_s4 = (const float4*)W_s;
        const float4* X_s4 = (const float4*)X_s;
        #pragma unroll 8
        for (int k4 = 0; k4 < 32; ++k4) {
            float4 w = W_s4[tid * WPAD + k4];   // start bank 4*(o+k4): cf-free
            #pragma unroll
            for (int j = 0; j < PPB; ++j) {
                float4 e = X_s4[j * 32 + k4];   // broadcast
                acc[j] += e.x * w.x + e.y * w.y + e.z * w.z + e.w * w.w;
            }
        }
        #pragma unroll
        for (int j = 0; j < PPB; ++j)
            P[(size_t)(a0 + j) * LATDIM + tid] = acc[j];
    } else {
        const int t  = blockIdx.x - PBLK;
        const int s0 = t * SPB;
        int base[SPB];
        #pragma unroll
        for (int j = 0; j < SPB; ++j)
            base[j] = ((s0 + j) * ANUM) % NNODES;   // window start (always <N)

        // Phase 1: column sums of 4 disjoint 64-row windows (coalesced).
        float acc[SPB] = {};
        #pragma unroll 8
        for (int r = 0; r < ANUM; ++r) {
            #pragma unroll
            for (int j = 0; j < SPB; ++j) {
                int row = base[j] + r;
                if (row >= NNODES) row -= NNODES;
                acc[j] += embeds[(size_t)row * LATDIM + tid];
            }
        }
        #pragma unroll
        for (int j = 0; j < SPB; ++j) X_s[j][tid] = acc[j];
        __syncthreads();   // covers W_s too

        float acc2[SPB] = {};
        const float4* W_s4 = (const float4*)W_s;
        const float4* X_s4 = (const float4*)X_s;
        #pragma unroll 8
        for (int k4 = 0; k4 < 32; ++k4) {
            float4 w = W_s4[tid * WPAD + k4];
            #pragma unroll
            for (int j = 0; j < SPB; ++j) {
                float4 s = X_s4[j * 32 + k4];   // broadcast
                acc2[j] += s.x * w.x + s.y * w.y + s.z * w.z + s.w * w.w;
            }
        }
        const float bias = b[tid];
        #pragma unroll
        for (int j = 0; j < SPB; ++j) {
            int s = s0 + j;
            if (s < PERIOD)
                T2b[(size_t)s * LATDIM + tid] = bias + acc2[j] * (1.0f / ANUM);
        }
    }
}

// out[n,o] = (1/A) * sum_a dists[a,n] * P[a,o] + T2b[n%625, o]
// 256 threads = 4 waves: wave -> (o-half, 16-n chunk). d-values are
// wave-uniform (scalar-load path); P from LDS (b32, conflict-free).
__global__ __launch_bounds__(256) void main_kernel(
    const float* __restrict__ dists,    // [A, N] fp32
    const float* __restrict__ P,        // [A, d]
    const float* __restrict__ T2b,      // [625, d]
    float* __restrict__ out)            // [N, d] fp32
{
    __shared__ float P_s[ANUM * LATDIM];   // 32 KB
    const int tid = threadIdx.x;

    {   // stage P, coalesced float4
        float4* P_s4 = (float4*)P_s;
        const float4* Pg = (const float4*)P;
        #pragma unroll
        for (int it = 0; it < (ANUM * LATDIM / 4) / 256; ++it)
            P_s4[it * 256 + tid] = Pg[it * 256 + tid];
    }
    __syncthreads();

    const int lane = tid & 63;
    const int w    = __builtin_amdgcn_readfirstlane(tid >> 6);  // uniform 0..3
    const int o    = (w & 1) * 64 + lane;   // output channel
    const int nc   = w >> 1;                // n-chunk within block
    int nb = blockIdx.x * TN + nc * 16;     // uniform chunk base
    const bool live = (nb + 16) <= NNODES;  // chunks are 16-aligned; N%16==0
    if (!live) nb = NNODES - 16;            // clamp loads; stores guarded

    float acc[16] = {};
    for (int a = 0; a < ANUM; ++a) {
        const float p = P_s[a * LATDIM + o];                 // per-lane LDS
        const float* __restrict__ drow = dists + (size_t)a * NNODES + nb;
        #pragma unroll
        for (int j = 0; j < 16; ++j)
            acc[j] += drow[j] * p;                           // uniform loads
    }

    if (live) {
        #pragma unroll
        for (int j = 0; j < 16; ++j) {
            const int n = nb + j;
            const int s = n % PERIOD;
            out[(size_t)n * LATDIM + o] =
                acc[j] * (1.0f / ANUM) + T2b[(size_t)s * LATDIM + o];
        }
    }
}

extern "C" void kernel_launch(void* const* d_in, const int* in_sizes, int n_in,
                              void* d_out, int out_size, void* d_ws, size_t ws_size,
                              hipStream_t stream) {
    const float* embeds = (const float*)d_in[0];   // [10000,128] fp32
    const float* dists  = (const float*)d_in[1];   // [64,10000]  fp32
    const float* W      = (const float*)d_in[2];   // [128,256]   fp32
    const float* b      = (const float*)d_in[3];   // [128]       fp32
    const int*   anchor = (const int*)d_in[4];     // [64]        int32
    float* out = (float*)d_out;                    // [10000,128] fp32

    float* P   = (float*)d_ws;            // 64*128 floats   = 32 KB
    float* T2b = P + ANUM * LATDIM;       // 625*128 floats  = 320 KB

    prep_kernel<<<PBLK + TBLK, 128, 0, stream>>>(embeds, W, b, anchor, P, T2b);
    main_kernel<<<(NNODES + TN - 1) / TN, 256, 0, stream>>>(dists, P, T2b, out);
}